// Round 1
// baseline (1406.741 us; speedup 1.0000x reference)
//
// HNHN layer on MI355X (gfx950).
// Pipeline:
//   K0:  W0,W1 -> bf16 transposed (W0T/W1T, [n][k])
//   K1:  rowsum(B1) -> node_card = rowsum^-0.5
//   K2:  y0 = x0@W0 (MFMA); epilogue: y0sT[c][n] = bf16(node_card[n]*y0[n,c]) (transposed)
//   K2b: y0sT aux rows: 256=node_card, 257=1.0, 258..271=0
//   MM1: mm1p[sp] = B1^T @ y0s (split-K=2); aux cols -> d1sum, colsum partials
//        (A=B1^T staged via LDS transpose+convert w/ 16B-block XOR swizzle)
//   K3:  x1 = d1inv*(p0+p1)+b01; out1=relu(x1); x1bf=bf16(x1); edge_card=colsum^-1.5
//   K5:  y1 = x1@W1 (MFMA, A via global_load_lds); epilogue y1sT[c][e]=bf16(edge_card[e]*y1)
//   K5b: y1sT aux rows: 256=edge_card, 257..271=0
//   MM2: mm2raw = B1 @ y1s; aux col -> d0sum   (m97-style bt-GEMM, inline fp32->bf16 A)
//   K6:  out0 = relu(d0inv*mm2raw + b10)
#include <hip/hip_runtime.h>
#include <stdint.h>

#define NN 16384
#define NE 8192
#define CH 256

typedef __attribute__((ext_vector_type(8))) short bf16x8;
typedef __attribute__((ext_vector_type(4))) float f32x4;

__device__ __forceinline__ unsigned short f2bf(float f) {  // RNE fp32->bf16
  unsigned u = __float_as_uint(f);
  u += 0x7FFFu + ((u >> 16) & 1u);
  return (unsigned short)(u >> 16);
}
__device__ __forceinline__ unsigned pack_trunc2(float a, float b) {  // exact for 0/1
  return (__float_as_uint(b) & 0xFFFF0000u) | (__float_as_uint(a) >> 16);
}
__device__ __forceinline__ void async_copy16(const void* gptr, void* lptr) {
  __builtin_amdgcn_global_load_lds((const __attribute__((address_space(1))) unsigned int*)gptr,
                                   (__attribute__((address_space(3))) unsigned int*)lptr,
                                   16, 0, 0);
}

// ---------------- K0: weight transpose to bf16 ----------------
__global__ void k0_transpose_w(const float* __restrict__ W0, const float* __restrict__ W1,
                               unsigned short* __restrict__ W0T, unsigned short* __restrict__ W1T) {
  const float* W = blockIdx.y ? W1 : W0;
  unsigned short* WT = blockIdx.y ? W1T : W0T;
  int n = blockIdx.x;
  int k = threadIdx.x;
  WT[n * CH + k] = f2bf(W[k * CH + n]);
}

// ---------------- K1: node_card ----------------
__global__ void k1_node_card(const float* __restrict__ B1, float* __restrict__ node_card) {
  int n = blockIdx.x;
  const float4* row = (const float4*)(B1 + (size_t)n * NE);
  float s = 0.f;
#pragma unroll
  for (int j = 0; j < 8; ++j) {
    float4 v = row[threadIdx.x + j * 256];
    s += v.x + v.y + v.z + v.w;
  }
  __shared__ float red[4];
#pragma unroll
  for (int off = 32; off; off >>= 1) s += __shfl_down(s, off, 64);
  if ((threadIdx.x & 63) == 0) red[threadIdx.x >> 6] = s;
  __syncthreads();
  if (threadIdx.x == 0) {
    float t = red[0] + red[1] + red[2] + red[3];
    node_card[n] = rsqrtf(t);
  }
}

// ---------------- K2: y0 GEMM + scaled transpose epilogue ----------------
__global__ __launch_bounds__(256) void k2_y0(const float* __restrict__ X0,
                                             const unsigned short* __restrict__ W0T,
                                             const float* __restrict__ node_card,
                                             unsigned short* __restrict__ y0sT) {
  __shared__ unsigned short a_lds[64 * 32];
  __shared__ unsigned short b_lds[256 * 32];
  const int tid = threadIdx.x;
  const int wave = tid >> 6, lane = tid & 63;
  const int quad = lane >> 4, l15 = lane & 15;
  const int m0 = blockIdx.x * 64;
  const int ar = tid >> 3, ac = (tid & 7) * 4;

  f32x4 acc[4][4];
  const f32x4 fz = {0.f, 0.f, 0.f, 0.f};
#pragma unroll
  for (int i = 0; i < 4; ++i)
#pragma unroll
    for (int j = 0; j < 4; ++j) acc[i][j] = fz;

  for (int k0 = 0; k0 < CH; k0 += 32) {
    __syncthreads();
#pragma unroll
    for (int p = 0; p < 2; ++p) {
      float4 v = *(const float4*)(X0 + (size_t)(m0 + ar + p * 32) * CH + k0 + ac);
      uint2 w;
      w.x = ((unsigned)f2bf(v.x)) | ((unsigned)f2bf(v.y) << 16);
      w.y = ((unsigned)f2bf(v.z)) | ((unsigned)f2bf(v.w) << 16);
      *(uint2*)&a_lds[(ar + p * 32) * 32 + ac] = w;
    }
#pragma unroll
    for (int i = 0; i < 4; ++i) {
      int rowbase = wave * 64 + i * 16;
      const unsigned short* g = W0T + (size_t)(rowbase + (lane >> 2)) * CH + k0 + (lane & 3) * 8;
      async_copy16(g, &b_lds[rowbase * 32]);
    }
    __syncthreads();
    bf16x8 af[4];
#pragma unroll
    for (int i = 0; i < 4; ++i)
      af[i] = *(const bf16x8*)&a_lds[(i * 16 + l15) * 32 + quad * 8];
#pragma unroll
    for (int j = 0; j < 4; ++j) {
      bf16x8 bfr = *(const bf16x8*)&b_lds[(wave * 64 + j * 16 + l15) * 32 + quad * 8];
#pragma unroll
      for (int i = 0; i < 4; ++i)
        acc[i][j] = __builtin_amdgcn_mfma_f32_16x16x32_bf16(af[i], bfr, acc[i][j], 0, 0, 0);
    }
  }
#pragma unroll
  for (int i = 0; i < 4; ++i) {
    int row4 = m0 + i * 16 + quad * 4;
    float4 nc = *(const float4*)(node_card + row4);
#pragma unroll
    for (int j = 0; j < 4; ++j) {
      int col = wave * 64 + j * 16 + l15;
      f32x4 v = acc[i][j];
      ushort4 o;
      o.x = f2bf(v[0] * nc.x);
      o.y = f2bf(v[1] * nc.y);
      o.z = f2bf(v[2] * nc.z);
      o.w = f2bf(v[3] * nc.w);
      *(ushort4*)&y0sT[(size_t)col * NN + row4] = o;
    }
  }
}

// ---------------- K2b: y0sT aux rows ----------------
__global__ void k2b_aux(const float* __restrict__ node_card, unsigned short* __restrict__ y0sT) {
  int n = blockIdx.x * 256 + threadIdx.x;
  y0sT[(size_t)256 * NN + n] = f2bf(node_card[n]);
  y0sT[(size_t)257 * NN + n] = 0x3F80;  // 1.0 bf16
#pragma unroll
  for (int r = 258; r < 272; ++r) y0sT[(size_t)r * NN + n] = 0;
}

// ---------------- MM1: B1^T @ y0s (split-K=2) ----------------
__global__ __launch_bounds__(256) void mm1_kernel(const float* __restrict__ B1,
                                                  const unsigned short* __restrict__ y0sT,
                                                  float* __restrict__ mm1p,
                                                  float* __restrict__ auxD,
                                                  float* __restrict__ auxC) {
  __shared__ unsigned short a_lds[64 * 32];
  __shared__ unsigned short b_lds[272 * 32];
  const int tid = threadIdx.x;
  const int wave = tid >> 6, lane = tid & 63;
  const int quad = lane >> 4, l15 = lane & 15;
  const int m0 = blockIdx.x * 64;  // e-range
  const int sp = blockIdx.y;
  const int kbase = sp * (NN / 2);

  const int am4 = (tid & 15) * 4;
  const int anp = tid >> 4;  // kword index 0..15
  const int ajb = anp >> 2, alow = anp & 3;

  f32x4 acc[4][4];
  f32x4 acc5[4];
  const f32x4 fz = {0.f, 0.f, 0.f, 0.f};
#pragma unroll
  for (int i = 0; i < 4; ++i) {
    acc5[i] = fz;
#pragma unroll
    for (int j = 0; j < 4; ++j) acc[i][j] = fz;
  }

  const float* agp = B1 + (size_t)(kbase + 2 * anp) * NE + m0 + am4;

  for (int kk = 0; kk < NN / 2; kk += 32) {
    const int k0 = kbase + kk;
    __syncthreads();
    // A stage: transpose+convert B1[k0..k0+31][m0..m0+63] -> a_lds[m][k], XOR-swizzled 16B blocks
    {
      float4 va = *(const float4*)(agp);
      float4 vb = *(const float4*)(agp + NE);
      agp += (size_t)32 * NE;
#pragma unroll
      for (int i = 0; i < 4; ++i) {
        int m = am4 + i;
        unsigned w = pack_trunc2(((const float*)&va)[i], ((const float*)&vb)[i]);
        int jbs = ajb ^ ((m >> 2) & 3);
        *(unsigned*)&a_lds[m * 32 + (jbs * 4 + alow) * 2] = w;
      }
    }
    // B stage (global_load_lds, 16B/lane)
#pragma unroll
    for (int i = 0; i < 4; ++i) {
      int rowbase = wave * 64 + i * 16;
      const unsigned short* g = y0sT + (size_t)(rowbase + (lane >> 2)) * NN + k0 + (lane & 3) * 8;
      async_copy16(g, &b_lds[rowbase * 32]);
    }
    if (wave == 3) {
      const unsigned short* g = y0sT + (size_t)(256 + (lane >> 2)) * NN + k0 + (lane & 3) * 8;
      async_copy16(g, &b_lds[256 * 32]);
    }
    __syncthreads();
    bf16x8 af[4];
#pragma unroll
    for (int i = 0; i < 4; ++i) {
      int m = i * 16 + l15;
      int jbs = quad ^ ((m >> 2) & 3);
      af[i] = *(const bf16x8*)&a_lds[m * 32 + jbs * 8];
    }
#pragma unroll
    for (int j = 0; j < 4; ++j) {
      bf16x8 bfr = *(const bf16x8*)&b_lds[(wave * 64 + j * 16 + l15) * 32 + quad * 8];
#pragma unroll
      for (int i = 0; i < 4; ++i)
        acc[i][j] = __builtin_amdgcn_mfma_f32_16x16x32_bf16(af[i], bfr, acc[i][j], 0, 0, 0);
    }
    if (wave == 3) {
      bf16x8 bfr = *(const bf16x8*)&b_lds[(256 + l15) * 32 + quad * 8];
#pragma unroll
      for (int i = 0; i < 4; ++i)
        acc5[i] = __builtin_amdgcn_mfma_f32_16x16x32_bf16(af[i], bfr, acc5[i], 0, 0, 0);
    }
  }
  float* outp = mm1p + (size_t)sp * NE * CH;
#pragma unroll
  for (int i = 0; i < 4; ++i) {
    int row4 = m0 + i * 16 + quad * 4;
#pragma unroll
    for (int j = 0; j < 4; ++j) {
      int col = wave * 64 + j * 16 + l15;
#pragma unroll
      for (int r = 0; r < 4; ++r) outp[(size_t)(row4 + r) * CH + col] = acc[i][j][r];
    }
  }
  if (wave == 3 && l15 < 2) {
    float* dst = (l15 == 0 ? auxD : auxC) + (size_t)sp * NE;
#pragma unroll
    for (int i = 0; i < 4; ++i) {
      int row4 = m0 + i * 16 + quad * 4;
#pragma unroll
      for (int r = 0; r < 4; ++r) dst[row4 + r] = acc5[i][r];
    }
  }
}

// ---------------- K3: edge finalize ----------------
__global__ void k3_edge_final(const float* __restrict__ mm1p, const float* __restrict__ auxD,
                              const float* __restrict__ auxC, const float* __restrict__ b01,
                              float* __restrict__ out1, unsigned short* __restrict__ x1bf,
                              float* __restrict__ edge_card) {
  int e = blockIdx.x, c = threadIdx.x;
  float d1 = 1.0f / (auxD[e] + auxD[NE + e]);
  float p = mm1p[(size_t)e * CH + c] + mm1p[(size_t)(NE + e) * CH + c];
  float x1 = d1 * p + b01[c];
  out1[(size_t)e * CH + c] = fmaxf(x1, 0.f);
  x1bf[(size_t)e * CH + c] = f2bf(x1);
  if (c == 0) {
    float cs = auxC[e] + auxC[NE + e];
    edge_card[e] = 1.0f / (cs * sqrtf(cs));
  }
}

// ---------------- K5: y1 GEMM + scaled transpose epilogue ----------------
__global__ __launch_bounds__(256) void k5_y1(const unsigned short* __restrict__ x1bf,
                                             const unsigned short* __restrict__ W1T,
                                             const float* __restrict__ edge_card,
                                             unsigned short* __restrict__ y1sT) {
  __shared__ unsigned short a_lds[64 * 32];
  __shared__ unsigned short b_lds[256 * 32];
  const int tid = threadIdx.x;
  const int wave = tid >> 6, lane = tid & 63;
  const int quad = lane >> 4, l15 = lane & 15;
  const int m0 = blockIdx.x * 64;  // e-range

  f32x4 acc[4][4];
  const f32x4 fz = {0.f, 0.f, 0.f, 0.f};
#pragma unroll
  for (int i = 0; i < 4; ++i)
#pragma unroll
    for (int j = 0; j < 4; ++j) acc[i][j] = fz;

  for (int k0 = 0; k0 < CH; k0 += 32) {
    __syncthreads();
    {  // A: bf16 already, async copy. 16 rows per wave.
      int arow = wave * 16 + (lane >> 2);
      const unsigned short* g = x1bf + (size_t)(m0 + arow) * CH + k0 + (lane & 3) * 8;
      async_copy16(g, &a_lds[(wave * 16) * 32]);
    }
#pragma unroll
    for (int i = 0; i < 4; ++i) {
      int rowbase = wave * 64 + i * 16;
      const unsigned short* g = W1T + (size_t)(rowbase + (lane >> 2)) * CH + k0 + (lane & 3) * 8;
      async_copy16(g, &b_lds[rowbase * 32]);
    }
    __syncthreads();
    bf16x8 af[4];
#pragma unroll
    for (int i = 0; i < 4; ++i)
      af[i] = *(const bf16x8*)&a_lds[(i * 16 + l15) * 32 + quad * 8];
#pragma unroll
    for (int j = 0; j < 4; ++j) {
      bf16x8 bfr = *(const bf16x8*)&b_lds[(wave * 64 + j * 16 + l15) * 32 + quad * 8];
#pragma unroll
      for (int i = 0; i < 4; ++i)
        acc[i][j] = __builtin_amdgcn_mfma_f32_16x16x32_bf16(af[i], bfr, acc[i][j], 0, 0, 0);
    }
  }
#pragma unroll
  for (int i = 0; i < 4; ++i) {
    int row4 = m0 + i * 16 + quad * 4;
    float4 ec = *(const float4*)(edge_card + row4);
#pragma unroll
    for (int j = 0; j < 4; ++j) {
      int col = wave * 64 + j * 16 + l15;
      f32x4 v = acc[i][j];
      ushort4 o;
      o.x = f2bf(v[0] * ec.x);
      o.y = f2bf(v[1] * ec.y);
      o.z = f2bf(v[2] * ec.z);
      o.w = f2bf(v[3] * ec.w);
      *(ushort4*)&y1sT[(size_t)col * NE + row4] = o;
    }
  }
}

// ---------------- K5b: y1sT aux rows ----------------
__global__ void k5b_aux(const float* __restrict__ edge_card, unsigned short* __restrict__ y1sT) {
  int e = blockIdx.x * 256 + threadIdx.x;
  y1sT[(size_t)256 * NE + e] = f2bf(edge_card[e]);
#pragma unroll
  for (int r = 257; r < 272; ++r) y1sT[(size_t)r * NE + e] = 0;
}

// ---------------- MM2: B1 @ y1s ----------------
__global__ __launch_bounds__(256) void mm2_kernel(const float* __restrict__ B1,
                                                  const unsigned short* __restrict__ y1sT,
                                                  float* __restrict__ mm2raw,
                                                  float* __restrict__ d0sum) {
  __shared__ unsigned short a_lds[64 * 32];
  __shared__ unsigned short b_lds[272 * 32];
  const int tid = threadIdx.x;
  const int wave = tid >> 6, lane = tid & 63;
  const int quad = lane >> 4, l15 = lane & 15;
  const int m0 = blockIdx.x * 64;  // node-range
  const int ar = tid >> 3, ac = (tid & 7) * 4;

  f32x4 acc[4][4];
  f32x4 acc5[4];
  const f32x4 fz = {0.f, 0.f, 0.f, 0.f};
#pragma unroll
  for (int i = 0; i < 4; ++i) {
    acc5[i] = fz;
#pragma unroll
    for (int j = 0; j < 4; ++j) acc[i][j] = fz;
  }

  const float* agp = B1 + (size_t)(m0 + ar) * NE + ac;

  for (int k0 = 0; k0 < NE; k0 += 32) {
    __syncthreads();
#pragma unroll
    for (int p = 0; p < 2; ++p) {
      float4 v = *(const float4*)(agp + (size_t)(p * 32) * NE + k0);
      uint2 w;
      w.x = pack_trunc2(v.x, v.y);
      w.y = pack_trunc2(v.z, v.w);
      *(uint2*)&a_lds[(ar + p * 32) * 32 + ac] = w;
    }
#pragma unroll
    for (int i = 0; i < 4; ++i) {
      int rowbase = wave * 64 + i * 16;
      const unsigned short* g = y1sT + (size_t)(rowbase + (lane >> 2)) * NE + k0 + (lane & 3) * 8;
      async_copy16(g, &b_lds[rowbase * 32]);
    }
    if (wave == 3) {
      const unsigned short* g = y1sT + (size_t)(256 + (lane >> 2)) * NE + k0 + (lane & 3) * 8;
      async_copy16(g, &b_lds[256 * 32]);
    }
    __syncthreads();
    bf16x8 af[4];
#pragma unroll
    for (int i = 0; i < 4; ++i)
      af[i] = *(const bf16x8*)&a_lds[(i * 16 + l15) * 32 + quad * 8];
#pragma unroll
    for (int j = 0; j < 4; ++j) {
      bf16x8 bfr = *(const bf16x8*)&b_lds[(wave * 64 + j * 16 + l15) * 32 + quad * 8];
#pragma unroll
      for (int i = 0; i < 4; ++i)
        acc[i][j] = __builtin_amdgcn_mfma_f32_16x16x32_bf16(af[i], bfr, acc[i][j], 0, 0, 0);
    }
    if (wave == 3) {
      bf16x8 bfr = *(const bf16x8*)&b_lds[(256 + l15) * 32 + quad * 8];
#pragma unroll
      for (int i = 0; i < 4; ++i)
        acc5[i] = __builtin_amdgcn_mfma_f32_16x16x32_bf16(af[i], bfr, acc5[i], 0, 0, 0);
    }
  }
#pragma unroll
  for (int i = 0; i < 4; ++i) {
    int row4 = m0 + i * 16 + quad * 4;
#pragma unroll
    for (int j = 0; j < 4; ++j) {
      int col = wave * 64 + j * 16 + l15;
#pragma unroll
      for (int r = 0; r < 4; ++r) mm2raw[(size_t)(row4 + r) * CH + col] = acc[i][j][r];
    }
  }
  if (wave == 3 && l15 == 0) {
#pragma unroll
    for (int i = 0; i < 4; ++i) {
      int row4 = m0 + i * 16 + quad * 4;
#pragma unroll
      for (int r = 0; r < 4; ++r) d0sum[row4 + r] = acc5[i][r];
    }
  }
}

// ---------------- K6: node finalize ----------------
__global__ void k6_node_final(const float* __restrict__ mm2raw, const float* __restrict__ d0sum,
                              const float* __restrict__ b10, float* __restrict__ out0) {
  int n = blockIdx.x, c = threadIdx.x;
  float v = mm2raw[(size_t)n * CH + c] / d0sum[n] + b10[c];
  out0[(size_t)n * CH + c] = fmaxf(v, 0.f);
}

extern "C" void kernel_launch(void* const* d_in, const int* in_sizes, int n_in,
                              void* d_out, int out_size, void* d_ws, size_t ws_size,
                              hipStream_t stream) {
  const float* x0 = (const float*)d_in[0];
  const float* B1 = (const float*)d_in[1];
  const float* W0 = (const float*)d_in[2];
  const float* W1 = (const float*)d_in[3];
  const float* b01 = (const float*)d_in[4];
  const float* b10 = (const float*)d_in[5];
  float* out0 = (float*)d_out;
  float* out1 = out0 + (size_t)NN * CH;

  char* ws = (char*)d_ws;
  size_t off = 0;
  auto take = [&](size_t bytes) {
    void* p = ws + off;
    off += (bytes + 255) & ~(size_t)255;
    return p;
  };
  unsigned short* y0sT = (unsigned short*)take((size_t)272 * NN * 2);   // 8.9 MB
  unsigned short* y1sT = (unsigned short*)take((size_t)272 * NE * 2);   // 4.5 MB
  unsigned short* x1bf = (unsigned short*)take((size_t)NE * CH * 2);    // 4.2 MB
  float* mm1p = (float*)take((size_t)2 * NE * CH * 4);                  // 16.8 MB
  float* mm2raw = (float*)take((size_t)NN * CH * 4);                    // 16.8 MB
  float* node_card = (float*)take((size_t)NN * 4);
  float* edge_card = (float*)take((size_t)NE * 4);
  float* auxD = (float*)take((size_t)2 * NE * 4);
  float* auxC = (float*)take((size_t)2 * NE * 4);
  float* d0sum = (float*)take((size_t)NN * 4);
  unsigned short* W0T = (unsigned short*)take((size_t)CH * CH * 2);
  unsigned short* W1T = (unsigned short*)take((size_t)CH * CH * 2);
  (void)ws_size; (void)in_sizes; (void)n_in; (void)out_size;

  k0_transpose_w<<<dim3(256, 2), 256, 0, stream>>>(W0, W1, W0T, W1T);
  k1_node_card<<<NN, 256, 0, stream>>>(B1, node_card);
  k2_y0<<<NN / 64, 256, 0, stream>>>(x0, W0T, node_card, y0sT);
  k2b_aux<<<NN / 256, 256, 0, stream>>>(node_card, y0sT);
  mm1_kernel<<<dim3(NE / 64, 2), 256, 0, stream>>>(B1, y0sT, mm1p, auxD, auxC);
  k3_edge_final<<<NE, 256, 0, stream>>>(mm1p, auxD, auxC, b01, out1, x1bf, edge_card);
  k5_y1<<<NE / 64, 256, 0, stream>>>(x1bf, W1T, edge_card, y1sT);
  k5b_aux<<<NE / 256, 256, 0, stream>>>(edge_card, y1sT);
  mm2_kernel<<<NN / 64, 256, 0, stream>>>(B1, y1sT, mm2raw, d0sum);
  k6_node_final<<<NN, 256, 0, stream>>>(mm2raw, d0sum, b10, out0);
}

// Round 2
// 1147.252 us; speedup vs baseline: 1.2262x; 1.2262x over previous
//
// HNHN layer on MI355X (gfx950). Round 2: split-K + A-prefetch for MM1/MM2,
// conflict-free a_lds staging swizzle (stride 40 shorts, g(m)=(m>>4)&3).
// Pipeline:
//   K0:  W0,W1 -> bf16 transposed (W0T/W1T, [n][k])
//   K1:  rowsum(B1) -> node_card = rowsum^-0.5
//   K2:  y0 = x0@W0 (MFMA); epilogue: y0sT[c][n] = bf16(node_card[n]*y0[n,c])
//   K2b: y0sT aux rows: 256=node_card, 257=1.0, 258..271=0
//   MM1: mm1p[sp] = B1^T-slice @ y0s (split-K=8, 1024 blocks); aux -> d1/colsum partials
//   K3:  x1 = d1inv*sum(p)+b01; out1=relu(x1); x1bf=bf16(x1); edge_card=colsum^-1.5
//   K5:  y1 = x1@W1 (MFMA); epilogue y1sT[c][e]=bf16(edge_card[e]*y1)
//   K5b: y1sT aux rows
//   MM2: mm2p[sp] = B1-slice @ y1s (split-K=4, 1024 blocks); aux -> d0sum partials
//   K6:  out0 = relu(sum(mm2p)/sum(d0p) + b10)
#include <hip/hip_runtime.h>
#include <stdint.h>

#define NN 16384
#define NE 8192
#define CH 256
#define MM1_SPLIT 8
#define MM2_SPLIT 4

typedef __attribute__((ext_vector_type(8))) short bf16x8;
typedef __attribute__((ext_vector_type(4))) float f32x4;

__device__ __forceinline__ unsigned short f2bf(float f) {  // RNE fp32->bf16
  unsigned u = __float_as_uint(f);
  u += 0x7FFFu + ((u >> 16) & 1u);
  return (unsigned short)(u >> 16);
}
__device__ __forceinline__ unsigned pack_trunc2(float a, float b) {  // exact for 0/1
  return (__float_as_uint(b) & 0xFFFF0000u) | (__float_as_uint(a) >> 16);
}
__device__ __forceinline__ void async_copy16(const void* gptr, void* lptr) {
  __builtin_amdgcn_global_load_lds((const __attribute__((address_space(1))) unsigned int*)gptr,
                                   (__attribute__((address_space(3))) unsigned int*)lptr,
                                   16, 0, 0);
}

// ---------------- K0: weight transpose to bf16 ----------------
__global__ void k0_transpose_w(const float* __restrict__ W0, const float* __restrict__ W1,
                               unsigned short* __restrict__ W0T, unsigned short* __restrict__ W1T) {
  const float* W = blockIdx.y ? W1 : W0;
  unsigned short* WT = blockIdx.y ? W1T : W0T;
  int n = blockIdx.x;
  int k = threadIdx.x;
  WT[n * CH + k] = f2bf(W[k * CH + n]);
}

// ---------------- K1: node_card ----------------
__global__ void k1_node_card(const float* __restrict__ B1, float* __restrict__ node_card) {
  int n = blockIdx.x;
  const float4* row = (const float4*)(B1 + (size_t)n * NE);
  float s = 0.f;
#pragma unroll
  for (int j = 0; j < 8; ++j) {
    float4 v = row[threadIdx.x + j * 256];
    s += v.x + v.y + v.z + v.w;
  }
  __shared__ float red[4];
#pragma unroll
  for (int off = 32; off; off >>= 1) s += __shfl_down(s, off, 64);
  if ((threadIdx.x & 63) == 0) red[threadIdx.x >> 6] = s;
  __syncthreads();
  if (threadIdx.x == 0) {
    float t = red[0] + red[1] + red[2] + red[3];
    node_card[n] = rsqrtf(t);
  }
}

// ---------------- K2: y0 GEMM + scaled transpose epilogue ----------------
__global__ __launch_bounds__(256) void k2_y0(const float* __restrict__ X0,
                                             const unsigned short* __restrict__ W0T,
                                             const float* __restrict__ node_card,
                                             unsigned short* __restrict__ y0sT) {
  __shared__ unsigned short a_lds[64 * 32];
  __shared__ unsigned short b_lds[256 * 32];
  const int tid = threadIdx.x;
  const int wave = tid >> 6, lane = tid & 63;
  const int quad = lane >> 4, l15 = lane & 15;
  const int m0 = blockIdx.x * 64;
  const int ar = tid >> 3, ac = (tid & 7) * 4;

  f32x4 acc[4][4];
  const f32x4 fz = {0.f, 0.f, 0.f, 0.f};
#pragma unroll
  for (int i = 0; i < 4; ++i)
#pragma unroll
    for (int j = 0; j < 4; ++j) acc[i][j] = fz;

  for (int k0 = 0; k0 < CH; k0 += 32) {
    __syncthreads();
#pragma unroll
    for (int p = 0; p < 2; ++p) {
      float4 v = *(const float4*)(X0 + (size_t)(m0 + ar + p * 32) * CH + k0 + ac);
      uint2 w;
      w.x = ((unsigned)f2bf(v.x)) | ((unsigned)f2bf(v.y) << 16);
      w.y = ((unsigned)f2bf(v.z)) | ((unsigned)f2bf(v.w) << 16);
      *(uint2*)&a_lds[(ar + p * 32) * 32 + ac] = w;
    }
#pragma unroll
    for (int i = 0; i < 4; ++i) {
      int rowbase = wave * 64 + i * 16;
      const unsigned short* g = W0T + (size_t)(rowbase + (lane >> 2)) * CH + k0 + (lane & 3) * 8;
      async_copy16(g, &b_lds[rowbase * 32]);
    }
    __syncthreads();
    bf16x8 af[4];
#pragma unroll
    for (int i = 0; i < 4; ++i)
      af[i] = *(const bf16x8*)&a_lds[(i * 16 + l15) * 32 + quad * 8];
#pragma unroll
    for (int j = 0; j < 4; ++j) {
      bf16x8 bfr = *(const bf16x8*)&b_lds[(wave * 64 + j * 16 + l15) * 32 + quad * 8];
#pragma unroll
      for (int i = 0; i < 4; ++i)
        acc[i][j] = __builtin_amdgcn_mfma_f32_16x16x32_bf16(af[i], bfr, acc[i][j], 0, 0, 0);
    }
  }
#pragma unroll
  for (int i = 0; i < 4; ++i) {
    int row4 = m0 + i * 16 + quad * 4;
    float4 nc = *(const float4*)(node_card + row4);
#pragma unroll
    for (int j = 0; j < 4; ++j) {
      int col = wave * 64 + j * 16 + l15;
      f32x4 v = acc[i][j];
      ushort4 o;
      o.x = f2bf(v[0] * nc.x);
      o.y = f2bf(v[1] * nc.y);
      o.z = f2bf(v[2] * nc.z);
      o.w = f2bf(v[3] * nc.w);
      *(ushort4*)&y0sT[(size_t)col * NN + row4] = o;
    }
  }
}

// ---------------- K2b: y0sT aux rows ----------------
__global__ void k2b_aux(const float* __restrict__ node_card, unsigned short* __restrict__ y0sT) {
  int n = blockIdx.x * 256 + threadIdx.x;
  y0sT[(size_t)256 * NN + n] = f2bf(node_card[n]);
  y0sT[(size_t)257 * NN + n] = 0x3F80;  // 1.0 bf16
#pragma unroll
  for (int r = 258; r < 272; ++r) y0sT[(size_t)r * NN + n] = 0;
}

// ---------------- MM1: B1^T @ y0s (split-K=8, A-prefetch, 2-way-free swizzle) ----
// a_lds row stride 40 shorts (20 words): bank = f(l&1) spreads bit4;
// swizzle g(m)=(m>>4)&3 puts l>>2 into bank bits 2-3 -> store = 32 banks, 2-way (free).
__global__ __launch_bounds__(256) void mm1_kernel(const float* __restrict__ B1,
                                                  const unsigned short* __restrict__ y0sT,
                                                  float* __restrict__ mm1p,
                                                  float* __restrict__ auxD,
                                                  float* __restrict__ auxC) {
  __shared__ unsigned short a_lds[64 * 40];
  __shared__ unsigned short b_lds[272 * 32];
  const int tid = threadIdx.x;
  const int wave = tid >> 6, lane = tid & 63;
  const int quad = lane >> 4, l15 = lane & 15;
  const int m0 = blockIdx.x * 64;  // e-range
  const int sp = blockIdx.y;
  const int KS = NN / MM1_SPLIT;   // 2048
  const int kbase = sp * KS;

  const int am4 = (tid & 15) * 4;
  const int anp = tid >> 4;  // kword index 0..15
  const int ajb = anp >> 2, alow = anp & 3;

  f32x4 acc[4][4];
  f32x4 acc5[4];
  const f32x4 fz = {0.f, 0.f, 0.f, 0.f};
#pragma unroll
  for (int i = 0; i < 4; ++i) {
    acc5[i] = fz;
#pragma unroll
    for (int j = 0; j < 4; ++j) acc[i][j] = fz;
  }

  const float* agp = B1 + (size_t)(kbase + 2 * anp) * NE + m0 + am4;
  float4 va = *(const float4*)(agp);
  float4 vb = *(const float4*)(agp + NE);

  for (int kk = 0; kk < KS; kk += 32) {
    const int k0 = kbase + kk;
    __syncthreads();
    // A stage: transpose+convert -> a_lds[m][k], stride-40, xor swizzle on (m>>4)
    {
#pragma unroll
      for (int i = 0; i < 4; ++i) {
        int m = am4 + i;
        unsigned w = pack_trunc2(((const float*)&va)[i], ((const float*)&vb)[i]);
        int jbs = ajb ^ ((m >> 4) & 3);
        *(unsigned*)&a_lds[m * 40 + (jbs * 4 + alow) * 2] = w;
      }
    }
    // B stage (global_load_lds, 16B/lane)
#pragma unroll
    for (int i = 0; i < 4; ++i) {
      int rowbase = wave * 64 + i * 16;
      const unsigned short* g = y0sT + (size_t)(rowbase + (lane >> 2)) * NN + k0 + (lane & 3) * 8;
      async_copy16(g, &b_lds[rowbase * 32]);
    }
    if (wave == 3) {
      const unsigned short* g = y0sT + (size_t)(256 + (lane >> 2)) * NN + k0 + (lane & 3) * 8;
      async_copy16(g, &b_lds[256 * 32]);
    }
    __syncthreads();
    // Prefetch next iteration's A (overlaps MFMA phase; uniform branch)
    if (kk + 32 < KS) {
      agp += (size_t)32 * NE;
      va = *(const float4*)(agp);
      vb = *(const float4*)(agp + NE);
    }
    bf16x8 af[4];
#pragma unroll
    for (int i = 0; i < 4; ++i) {
      int m = i * 16 + l15;
      int jbs = quad ^ ((m >> 4) & 3);  // = quad ^ i
      af[i] = *(const bf16x8*)&a_lds[m * 40 + jbs * 8];
    }
#pragma unroll
    for (int j = 0; j < 4; ++j) {
      bf16x8 bfr = *(const bf16x8*)&b_lds[(wave * 64 + j * 16 + l15) * 32 + quad * 8];
#pragma unroll
      for (int i = 0; i < 4; ++i)
        acc[i][j] = __builtin_amdgcn_mfma_f32_16x16x32_bf16(af[i], bfr, acc[i][j], 0, 0, 0);
    }
    if (wave == 3) {
      bf16x8 bfr = *(const bf16x8*)&b_lds[(256 + l15) * 32 + quad * 8];
#pragma unroll
      for (int i = 0; i < 4; ++i)
        acc5[i] = __builtin_amdgcn_mfma_f32_16x16x32_bf16(af[i], bfr, acc5[i], 0, 0, 0);
    }
  }
  float* outp = mm1p + (size_t)sp * NE * CH;
#pragma unroll
  for (int i = 0; i < 4; ++i) {
    int row4 = m0 + i * 16 + quad * 4;
#pragma unroll
    for (int j = 0; j < 4; ++j) {
      int col = wave * 64 + j * 16 + l15;
#pragma unroll
      for (int r = 0; r < 4; ++r) outp[(size_t)(row4 + r) * CH + col] = acc[i][j][r];
    }
  }
  if (wave == 3 && l15 < 2) {
    float* dst = (l15 == 0 ? auxD : auxC) + (size_t)sp * NE;
#pragma unroll
    for (int i = 0; i < 4; ++i) {
      int row4 = m0 + i * 16 + quad * 4;
#pragma unroll
      for (int r = 0; r < 4; ++r) dst[row4 + r] = acc5[i][r];
    }
  }
}

// ---------------- K3: edge finalize (reduce 8 partials) ----------------
__global__ void k3_edge_final(const float* __restrict__ mm1p, const float* __restrict__ auxD,
                              const float* __restrict__ auxC, const float* __restrict__ b01,
                              float* __restrict__ out1, unsigned short* __restrict__ x1bf,
                              float* __restrict__ edge_card) {
  int e = blockIdx.x, c = threadIdx.x;
  float ds = 0.f, p = 0.f;
#pragma unroll
  for (int sp = 0; sp < MM1_SPLIT; ++sp) {
    ds += auxD[(size_t)sp * NE + e];
    p += mm1p[(size_t)sp * NE * CH + (size_t)e * CH + c];
  }
  float x1 = p / ds + b01[c];
  out1[(size_t)e * CH + c] = fmaxf(x1, 0.f);
  x1bf[(size_t)e * CH + c] = f2bf(x1);
  if (c == 0) {
    float cs = 0.f;
#pragma unroll
    for (int sp = 0; sp < MM1_SPLIT; ++sp) cs += auxC[(size_t)sp * NE + e];
    edge_card[e] = 1.0f / (cs * sqrtf(cs));
  }
}

// ---------------- K5: y1 GEMM + scaled transpose epilogue ----------------
__global__ __launch_bounds__(256) void k5_y1(const unsigned short* __restrict__ x1bf,
                                             const unsigned short* __restrict__ W1T,
                                             const float* __restrict__ edge_card,
                                             unsigned short* __restrict__ y1sT) {
  __shared__ unsigned short a_lds[64 * 32];
  __shared__ unsigned short b_lds[256 * 32];
  const int tid = threadIdx.x;
  const int wave = tid >> 6, lane = tid & 63;
  const int quad = lane >> 4, l15 = lane & 15;
  const int m0 = blockIdx.x * 64;  // e-range

  f32x4 acc[4][4];
  const f32x4 fz = {0.f, 0.f, 0.f, 0.f};
#pragma unroll
  for (int i = 0; i < 4; ++i)
#pragma unroll
    for (int j = 0; j < 4; ++j) acc[i][j] = fz;

  for (int k0 = 0; k0 < CH; k0 += 32) {
    __syncthreads();
    {  // A: bf16 already, async copy. 16 rows per wave.
      const unsigned short* g = x1bf + (size_t)(m0 + wave * 16 + (lane >> 2)) * CH + k0 + (lane & 3) * 8;
      async_copy16(g, &a_lds[(wave * 16) * 32]);
    }
#pragma unroll
    for (int i = 0; i < 4; ++i) {
      int rowbase = wave * 64 + i * 16;
      const unsigned short* g = W1T + (size_t)(rowbase + (lane >> 2)) * CH + k0 + (lane & 3) * 8;
      async_copy16(g, &b_lds[rowbase * 32]);
    }
    __syncthreads();
    bf16x8 af[4];
#pragma unroll
    for (int i = 0; i < 4; ++i)
      af[i] = *(const bf16x8*)&a_lds[(i * 16 + l15) * 32 + quad * 8];
#pragma unroll
    for (int j = 0; j < 4; ++j) {
      bf16x8 bfr = *(const bf16x8*)&b_lds[(wave * 64 + j * 16 + l15) * 32 + quad * 8];
#pragma unroll
      for (int i = 0; i < 4; ++i)
        acc[i][j] = __builtin_amdgcn_mfma_f32_16x16x32_bf16(af[i], bfr, acc[i][j], 0, 0, 0);
    }
  }
#pragma unroll
  for (int i = 0; i < 4; ++i) {
    int row4 = m0 + i * 16 + quad * 4;
    float4 ec = *(const float4*)(edge_card + row4);
#pragma unroll
    for (int j = 0; j < 4; ++j) {
      int col = wave * 64 + j * 16 + l15;
      f32x4 v = acc[i][j];
      ushort4 o;
      o.x = f2bf(v[0] * ec.x);
      o.y = f2bf(v[1] * ec.y);
      o.z = f2bf(v[2] * ec.z);
      o.w = f2bf(v[3] * ec.w);
      *(ushort4*)&y1sT[(size_t)col * NE + row4] = o;
    }
  }
}

// ---------------- K5b: y1sT aux rows ----------------
__global__ void k5b_aux(const float* __restrict__ edge_card, unsigned short* __restrict__ y1sT) {
  int e = blockIdx.x * 256 + threadIdx.x;
  y1sT[(size_t)256 * NE + e] = f2bf(edge_card[e]);
#pragma unroll
  for (int r = 257; r < 272; ++r) y1sT[(size_t)r * NE + e] = 0;
}

// ---------------- MM2: B1 @ y1s (split-K=4, A-prefetch, stride-40 a_lds) -------
__global__ __launch_bounds__(256) void mm2_kernel(const float* __restrict__ B1,
                                                  const unsigned short* __restrict__ y1sT,
                                                  float* __restrict__ mm2p,
                                                  float* __restrict__ d0p) {
  __shared__ unsigned short a_lds[64 * 40];
  __shared__ unsigned short b_lds[272 * 32];
  const int tid = threadIdx.x;
  const int wave = tid >> 6, lane = tid & 63;
  const int quad = lane >> 4, l15 = lane & 15;
  const int m0 = blockIdx.x * 64;  // node-range
  const int sp = blockIdx.y;
  const int KS = NE / MM2_SPLIT;   // 2048
  const int kbase = sp * KS;
  const int ar = tid >> 3, ac = (tid & 7) * 4;

  f32x4 acc[4][4];
  f32x4 acc5[4];
  const f32x4 fz = {0.f, 0.f, 0.f, 0.f};
#pragma unroll
  for (int i = 0; i < 4; ++i) {
    acc5[i] = fz;
#pragma unroll
    for (int j = 0; j < 4; ++j) acc[i][j] = fz;
  }

  const float* agp = B1 + (size_t)(m0 + ar) * NE + kbase + ac;
  float4 va = *(const float4*)(agp);
  float4 vb = *(const float4*)(agp + (size_t)32 * NE);

  for (int kk = 0; kk < KS; kk += 32) {
    const int k0 = kbase + kk;
    __syncthreads();
    {
      uint2 w0, w1;
      w0.x = pack_trunc2(va.x, va.y);
      w0.y = pack_trunc2(va.z, va.w);
      w1.x = pack_trunc2(vb.x, vb.y);
      w1.y = pack_trunc2(vb.z, vb.w);
      *(uint2*)&a_lds[ar * 40 + ac] = w0;
      *(uint2*)&a_lds[(ar + 32) * 40 + ac] = w1;
    }
#pragma unroll
    for (int i = 0; i < 4; ++i) {
      int rowbase = wave * 64 + i * 16;
      const unsigned short* g = y1sT + (size_t)(rowbase + (lane >> 2)) * NE + k0 + (lane & 3) * 8;
      async_copy16(g, &b_lds[rowbase * 32]);
    }
    if (wave == 3) {
      const unsigned short* g = y1sT + (size_t)(256 + (lane >> 2)) * NE + k0 + (lane & 3) * 8;
      async_copy16(g, &b_lds[256 * 32]);
    }
    __syncthreads();
    // Prefetch next iteration's A (overlaps MFMA phase; uniform branch)
    if (kk + 32 < KS) {
      agp += 32;
      va = *(const float4*)(agp);
      vb = *(const float4*)(agp + (size_t)32 * NE);
    }
    bf16x8 af[4];
#pragma unroll
    for (int i = 0; i < 4; ++i)
      af[i] = *(const bf16x8*)&a_lds[(i * 16 + l15) * 40 + quad * 8];
#pragma unroll
    for (int j = 0; j < 4; ++j) {
      bf16x8 bfr = *(const bf16x8*)&b_lds[(wave * 64 + j * 16 + l15) * 32 + quad * 8];
#pragma unroll
      for (int i = 0; i < 4; ++i)
        acc[i][j] = __builtin_amdgcn_mfma_f32_16x16x32_bf16(af[i], bfr, acc[i][j], 0, 0, 0);
    }
    if (wave == 3) {
      bf16x8 bfr = *(const bf16x8*)&b_lds[(256 + l15) * 32 + quad * 8];
#pragma unroll
      for (int i = 0; i < 4; ++i)
        acc5[i] = __builtin_amdgcn_mfma_f32_16x16x32_bf16(af[i], bfr, acc5[i], 0, 0, 0);
    }
  }
  float* outp = mm2p + (size_t)sp * NN * CH;
#pragma unroll
  for (int i = 0; i < 4; ++i) {
    int row4 = m0 + i * 16 + quad * 4;
#pragma unroll
    for (int j = 0; j < 4; ++j) {
      int col = wave * 64 + j * 16 + l15;
#pragma unroll
      for (int r = 0; r < 4; ++r) outp[(size_t)(row4 + r) * CH + col] = acc[i][j][r];
    }
  }
  if (wave == 3 && l15 == 0) {
#pragma unroll
    for (int i = 0; i < 4; ++i) {
      int row4 = m0 + i * 16 + quad * 4;
#pragma unroll
      for (int r = 0; r < 4; ++r) d0p[(size_t)sp * NN + row4 + r] = acc5[i][r];
    }
  }
}

// ---------------- K6: node finalize (reduce 4 partials) ----------------
__global__ void k6_node_final(const float* __restrict__ mm2p, const float* __restrict__ d0p,
                              const float* __restrict__ b10, float* __restrict__ out0) {
  int n = blockIdx.x, c = threadIdx.x;
  float s = 0.f, d = 0.f;
#pragma unroll
  for (int sp = 0; sp < MM2_SPLIT; ++sp) {
    s += mm2p[(size_t)sp * NN * CH + (size_t)n * CH + c];
    d += d0p[(size_t)sp * NN + n];
  }
  float v = s / d + b10[c];
  out0[(size_t)n * CH + c] = fmaxf(v, 0.f);
}

extern "C" void kernel_launch(void* const* d_in, const int* in_sizes, int n_in,
                              void* d_out, int out_size, void* d_ws, size_t ws_size,
                              hipStream_t stream) {
  const float* x0 = (const float*)d_in[0];
  const float* B1 = (const float*)d_in[1];
  const float* W0 = (const float*)d_in[2];
  const float* W1 = (const float*)d_in[3];
  const float* b01 = (const float*)d_in[4];
  const float* b10 = (const float*)d_in[5];
  float* out0 = (float*)d_out;
  float* out1 = out0 + (size_t)NN * CH;

  char* ws = (char*)d_ws;
  size_t off = 0;
  auto take = [&](size_t bytes) {
    void* p = ws + off;
    off += (bytes + 255) & ~(size_t)255;
    return p;
  };
  unsigned short* y0sT = (unsigned short*)take((size_t)272 * NN * 2);          // 8.9 MB
  unsigned short* y1sT = (unsigned short*)take((size_t)272 * NE * 2);          // 4.5 MB
  unsigned short* x1bf = (unsigned short*)take((size_t)NE * CH * 2);           // 4.2 MB
  float* mm1p = (float*)take((size_t)MM1_SPLIT * NE * CH * 4);                 // 67.1 MB
  float* mm2p = mm1p;  // alias: mm1p dead after K3; MM2_SPLIT*NN*CH*4 == same size
  float* node_card = (float*)take((size_t)NN * 4);
  float* edge_card = (float*)take((size_t)NE * 4);
  float* auxD = (float*)take((size_t)MM1_SPLIT * NE * 4);
  float* auxC = (float*)take((size_t)MM1_SPLIT * NE * 4);
  float* d0p = (float*)take((size_t)MM2_SPLIT * NN * 4);
  unsigned short* W0T = (unsigned short*)take((size_t)CH * CH * 2);
  unsigned short* W1T = (unsigned short*)take((size_t)CH * CH * 2);
  (void)ws_size; (void)in_sizes; (void)n_in; (void)out_size;

  k0_transpose_w<<<dim3(256, 2), 256, 0, stream>>>(W0, W1, W0T, W1T);
  k1_node_card<<<NN, 256, 0, stream>>>(B1, node_card);
  k2_y0<<<NN / 64, 256, 0, stream>>>(x0, W0T, node_card, y0sT);
  k2b_aux<<<NN / 256, 256, 0, stream>>>(node_card, y0sT);
  mm1_kernel<<<dim3(NE / 64, MM1_SPLIT), 256, 0, stream>>>(B1, y0sT, mm1p, auxD, auxC);
  k3_edge_final<<<NE, 256, 0, stream>>>(mm1p, auxD, auxC, b01, out1, x1bf, edge_card);
  k5_y1<<<NE / 64, 256, 0, stream>>>(x1bf, W1T, edge_card, y1sT);
  k5b_aux<<<NE / 256, 256, 0, stream>>>(edge_card, y1sT);
  mm2_kernel<<<dim3(NN / 64, MM2_SPLIT), 256, 0, stream>>>(B1, y1sT, mm2p, d0p);
  k6_node_final<<<NN, 256, 0, stream>>>(mm2p, d0p, b10, out0);
}